// Round 4
// baseline (113.695 us; speedup 1.0000x reference)
//
#include <hip/hip_runtime.h>
#include <hip/hip_fp16.h>

typedef _Float16 half8  __attribute__((ext_vector_type(8)));
typedef _Float16 half4v __attribute__((ext_vector_type(4)));
typedef float    f32x4  __attribute__((ext_vector_type(4)));

#define MFMA_F16 __builtin_amdgcn_mfma_f32_16x16x32_f16

// ---------------- kernel 0: W_q|W_k|W_v f32 -> concat f16 [384][1024] ----------------
__global__ __launch_bounds__(256) void wconv_k(const float* __restrict__ wq,
                                               const float* __restrict__ wk,
                                               const float* __restrict__ wv,
                                               _Float16* __restrict__ wh) {
    int i = (blockIdx.x * 256 + threadIdx.x) * 8;   // 393216 total elems
    const float* src; int off;
    if (i < 131072)      { src = wq; off = i; }
    else if (i < 262144) { src = wk; off = i - 131072; }
    else                 { src = wv; off = i - 262144; }
    float4 a = *(const float4*)(src + off);
    float4 b = *(const float4*)(src + off + 4);
    half8 h;
    h[0]=(_Float16)a.x; h[1]=(_Float16)a.y; h[2]=(_Float16)a.z; h[3]=(_Float16)a.w;
    h[4]=(_Float16)b.x; h[5]=(_Float16)b.y; h[6]=(_Float16)b.z; h[7]=(_Float16)b.w;
    *(half8*)(wh + i) = h;
}

// ---------------- kernel 1: fused QKV projection ----------------
// grid 512: rb=bid>>1 (64-row group), cb=bid&1 (192-col half). 256 thr = 4 waves.
__global__ __launch_bounds__(256, 2) void qkv_k(const float* __restrict__ x,
                                                const _Float16* __restrict__ wh,
                                                _Float16* __restrict__ qh,
                                                _Float16* __restrict__ kh,
                                                _Float16* __restrict__ vth) {
    __shared__ _Float16 xs[2][64 * 136];
    const int tid = threadIdx.x;
    const int w = tid >> 6, l = tid & 63;
    const int fr = l & 15, fq = l >> 4;
    const int rb = blockIdx.x >> 1, cb = blockIdx.x & 1;
    const int row0 = rb * 64;
    const int c0 = cb * 192 + w * 48;

    const int srow = tid >> 2, sg = tid & 3;
    const float* xg = x + (row0 + srow) * 1024 + sg * 4;
    const _Float16* wgb = wh + (c0 + fr) * 1024 + fq * 8;

    f32x4 acc[4][3] = {};
    float4 xa[8];
    half8 wf[2][3];

#pragma unroll
    for (int i = 0; i < 8; ++i) xa[i] = *(const float4*)(xg + i * 16);
#pragma unroll
    for (int i = 0; i < 8; ++i) {
        float4 t = xa[i]; half4v hv;
        hv[0]=(_Float16)t.x; hv[1]=(_Float16)t.y; hv[2]=(_Float16)t.z; hv[3]=(_Float16)t.w;
        *(half4v*)(&xs[0][srow * 136 + sg * 4 + i * 16]) = hv;
    }
#pragma unroll
    for (int i = 0; i < 8; ++i) xa[i] = *(const float4*)(xg + 128 + i * 16);
#pragma unroll
    for (int nf = 0; nf < 3; ++nf) wf[0][nf] = *(const half8*)(wgb + nf * 16384);
    __syncthreads();

    int cur = 0;
    for (int kt = 0; kt < 8; ++kt) {
        if (kt < 7) {
#pragma unroll
            for (int i = 0; i < 8; ++i) {
                float4 t = xa[i]; half4v hv;
                hv[0]=(_Float16)t.x; hv[1]=(_Float16)t.y; hv[2]=(_Float16)t.z; hv[3]=(_Float16)t.w;
                *(half4v*)(&xs[cur ^ 1][srow * 136 + sg * 4 + i * 16]) = hv;
            }
            if (kt < 6) {
#pragma unroll
                for (int i = 0; i < 8; ++i)
                    xa[i] = *(const float4*)(xg + (kt + 2) * 128 + i * 16);
            }
        }
#pragma unroll
        for (int s = 0; s < 4; ++s) {
            const int ss = kt * 4 + s;
            const int csw = ss & 1;
            if (ss + 1 < 32) {
#pragma unroll
                for (int nf = 0; nf < 3; ++nf)
                    wf[csw ^ 1][nf] = *(const half8*)(wgb + nf * 16384 + (ss + 1) * 32);
            }
            half8 af[4];
#pragma unroll
            for (int mf = 0; mf < 4; ++mf)
                af[mf] = *(const half8*)(&xs[cur][(mf * 16 + fr) * 136 + s * 32 + fq * 8]);
#pragma unroll
            for (int mf = 0; mf < 4; ++mf)
#pragma unroll
                for (int nf = 0; nf < 3; ++nf)
                    acc[mf][nf] = MFMA_F16(af[mf], wf[csw][nf], acc[mf][nf], 0, 0, 0);
        }
        __syncthreads();
        cur ^= 1;
    }

#pragma unroll
    for (int nf = 0; nf < 3; ++nf) {
        int n0 = c0 + nf * 16 + fr;
#pragma unroll
        for (int mf = 0; mf < 4; ++mf) {
            int mb = row0 + mf * 16 + fq * 4;
            if (n0 < 128) {
#pragma unroll
                for (int r = 0; r < 4; ++r) qh[(mb + r) * 128 + n0] = (_Float16)acc[mf][nf][r];
            } else if (n0 < 256) {
#pragma unroll
                for (int r = 0; r < 4; ++r) kh[(mb + r) * 128 + (n0 - 128)] = (_Float16)acc[mf][nf][r];
            } else {
                half4v pv;
#pragma unroll
                for (int r = 0; r < 4; ++r) pv[r] = (_Float16)acc[mf][nf][r];
                *(half4v*)(&vth[((mb >> 11) * 128 + (n0 - 256)) * 2048 + (mb & 2047)]) = pv;
            }
        }
    }
}

// ---------------- kernel 2: causal flash attention, split-KV (chunk = 8 kv-tiles) ----------------
// 640 blocks x 256 threads. bid: b = bid&7, unit u = bid>>3 in [0,80).
// nc(qt) = (qt>>3)+1. Single-chunk tiles (qt<8) write f32 directly to out.
// Multi-chunk write f16 partials in lane-contiguous permuted layout:
//   part[bid][w][dt][r][fq][fr]  (each store inst = 128B contiguous)
__global__ __launch_bounds__(256, 3) void attn_k(const _Float16* __restrict__ qh,
                                                 const _Float16* __restrict__ kh,
                                                 const _Float16* __restrict__ vth,
                                                 _Float16* __restrict__ part,
                                                 float* __restrict__ stats,
                                                 float* __restrict__ out) {
    __shared__ _Float16 ks[64 * 136];
    __shared__ _Float16 vs[128 * 72];
    __shared__ _Float16 ps[64 * 72];

    int bid = blockIdx.x;
    int b = bid & 7;
    int u = bid >> 3;
    int qt, c;
    if (u < 8)       { qt = u;                  c = 0; }
    else if (u < 24) { qt = 8  + ((u - 8) >> 1);  c = (u - 8) & 1; }
    else if (u < 48) { qt = 16 + (u - 24) / 3;    c = (u - 24) % 3; }
    else             { qt = 24 + ((u - 48) >> 2); c = (u - 48) & 3; }
    int j0 = c * 8;
    int j1 = j0 + 8 < qt + 1 ? j0 + 8 : qt + 1;

    int tid = threadIdx.x, w = tid >> 6, l = tid & 63;
    int fr = l & 15, fq = l >> 4;

    half8 qf[4];
    const _Float16* qp = qh + ((b * 2048 + qt * 64 + w * 16 + fr) << 7);
#pragma unroll
    for (int cc = 0; cc < 4; ++cc) qf[cc] = *(const half8*)(qp + cc * 32 + fq * 8);

    uint4 kreg[4], vreg[4];
#define LOAD_TILE(j) do {                                                                 \
    _Pragma("unroll")                                                                     \
    for (int uu = 0; uu < 4; ++uu) {                                                      \
        int ci = tid + uu * 256;                                                          \
        kreg[uu] = *(const uint4*)(kh + (((b << 11) + ((j) << 6) + (ci >> 4)) << 7) + (ci & 15) * 8); \
        vreg[uu] = *(const uint4*)(vth + ((((b << 7) + (ci >> 3)) << 11) + ((j) << 6) + (ci & 7) * 8)); \
    } } while (0)
#define WRITE_TILE() do {                                                                 \
    _Pragma("unroll")                                                                     \
    for (int uu = 0; uu < 4; ++uu) {                                                      \
        int ci = tid + uu * 256;                                                          \
        *(uint4*)(&ks[(ci >> 4) * 136 + (ci & 15) * 8]) = kreg[uu];                       \
        *(uint4*)(&vs[(ci >> 3) * 72 + (ci & 7) * 8]) = vreg[uu];                         \
    } } while (0)

    f32x4 acc[8] = {};
    float mrow[4], lrow[4];
#pragma unroll
    for (int r = 0; r < 4; ++r) { mrow[r] = -1e30f; lrow[r] = 0.0f; }

    LOAD_TILE(j0);
    WRITE_TILE();
    if (j0 + 1 < j1) LOAD_TILE(j0 + 1);
    __syncthreads();

    for (int j = j0; j < j1; ++j) {
        f32x4 s[4] = {};
#pragma unroll
        for (int n = 0; n < 4; ++n) {
#pragma unroll
            for (int cc = 0; cc < 4; ++cc) {
                half8 kf = *(const half8*)(&ks[(n * 16 + fr) * 136 + cc * 32 + fq * 8]);
                s[n] = MFMA_F16(qf[cc], kf, s[n], 0, 0, 0);
            }
        }
        const float sc = 0.088388347648318447f;  // 1/sqrt(128)
        if (j == qt) {
#pragma unroll
            for (int n = 0; n < 4; ++n)
#pragma unroll
                for (int r = 0; r < 4; ++r) {
                    int qrow = w * 16 + fq * 4 + r;
                    int kcol = n * 16 + fr;
                    float v = s[n][r] * sc;
                    s[n][r] = (kcol > qrow) ? -1e30f : v;
                }
        } else {
#pragma unroll
            for (int n = 0; n < 4; ++n)
#pragma unroll
                for (int r = 0; r < 4; ++r) s[n][r] *= sc;
        }

        float mx[4];
#pragma unroll
        for (int r = 0; r < 4; ++r)
            mx[r] = fmaxf(fmaxf(s[0][r], s[1][r]), fmaxf(s[2][r], s[3][r]));
#pragma unroll
        for (int off = 1; off < 16; off <<= 1)
#pragma unroll
            for (int r = 0; r < 4; ++r) mx[r] = fmaxf(mx[r], __shfl_xor(mx[r], off));
        float al[4];
#pragma unroll
        for (int r = 0; r < 4; ++r) {
            float nm = fmaxf(mrow[r], mx[r]);
            al[r] = __expf(mrow[r] - nm);
            mrow[r] = nm;
        }
        float rs[4] = {0.f, 0.f, 0.f, 0.f};
#pragma unroll
        for (int n = 0; n < 4; ++n)
#pragma unroll
            for (int r = 0; r < 4; ++r) {
                float p = __expf(s[n][r] - mrow[r]);
                s[n][r] = p;
                rs[r] += p;
            }
#pragma unroll
        for (int off = 1; off < 16; off <<= 1)
#pragma unroll
            for (int r = 0; r < 4; ++r) rs[r] += __shfl_xor(rs[r], off);
#pragma unroll
        for (int r = 0; r < 4; ++r) lrow[r] = lrow[r] * al[r] + rs[r];
#pragma unroll
        for (int dt = 0; dt < 8; ++dt)
#pragma unroll
            for (int r = 0; r < 4; ++r) acc[dt][r] *= al[r];

#pragma unroll
        for (int n = 0; n < 4; ++n)
#pragma unroll
            for (int r = 0; r < 4; ++r)
                ps[(w * 16 + fq * 4 + r) * 72 + n * 16 + fr] = (_Float16)s[n][r];

        half8 pa[2];
#pragma unroll
        for (int c2 = 0; c2 < 2; ++c2)
            pa[c2] = *(const half8*)(&ps[(w * 16 + fr) * 72 + c2 * 32 + fq * 8]);
#pragma unroll
        for (int dt = 0; dt < 8; ++dt)
#pragma unroll
            for (int c2 = 0; c2 < 2; ++c2) {
                half8 vf = *(const half8*)(&vs[(dt * 16 + fr) * 72 + c2 * 32 + fq * 8]);
                acc[dt] = MFMA_F16(pa[c2], vf, acc[dt], 0, 0, 0);
            }

        if (j + 1 < j1) {
            __syncthreads();
            WRITE_TILE();
            if (j + 2 < j1) LOAD_TILE(j + 2);
            __syncthreads();
        }
    }

    float inv[4];
#pragma unroll
    for (int r = 0; r < 4; ++r) inv[r] = 1.0f / lrow[r];

    if (qt < 8) {
        // single chunk: write final f32 output directly (full-line coalesced)
        float* op = out + ((b * 2048 + qt * 64 + w * 16 + fq * 4) << 7) + fr;
#pragma unroll
        for (int dt = 0; dt < 8; ++dt)
#pragma unroll
            for (int r = 0; r < 4; ++r)
                op[r * 128 + dt * 16] = acc[dt][r] * inv[r];
    } else {
        // permuted lane-contiguous partial: part[bid][w][dt][r][fq][fr]
        _Float16* op = part + bid * 8192 + w * 2048 + fq * 16 + fr;
#pragma unroll
        for (int dt = 0; dt < 8; ++dt)
#pragma unroll
            for (int r = 0; r < 4; ++r)
                op[dt * 256 + r * 64] = (_Float16)(acc[dt][r] * inv[r]);
        if (fr == 0) {
#pragma unroll
            for (int r = 0; r < 4; ++r) {
                int ridx = bid * 64 + w * 16 + fq * 4 + r;
                stats[ridx * 2]     = mrow[r];
                stats[ridx * 2 + 1] = lrow[r];
            }
        }
    }
#undef LOAD_TILE
#undef WRITE_TILE
}

// ---------------- kernel 3: combine split-KV partials (qt >= 8 only) ----------------
// 192 blocks (b, qt in [8,32)) x 256 threads. thread: row = t>>2, col group g = t&3.
__global__ __launch_bounds__(256) void comb_k(const _Float16* __restrict__ part,
                                              const float* __restrict__ stats,
                                              float* __restrict__ out) {
    int bid = blockIdx.x;
    int b = bid & 7, qt = 8 + (bid >> 3);
    int u0 = qt < 16 ? 8 + 2 * (qt - 8) : qt < 24 ? 24 + 3 * (qt - 16) : 48 + 4 * (qt - 24);
    int nc = qt < 16 ? 2 : qt < 24 ? 3 : 4;
    int t = threadIdx.x;
    int row = t >> 2, g = t & 3;
    int w = row >> 4, fq = (row >> 2) & 3, r = row & 3;

    float mstar = -1e30f, mv[4], lv[4];
#pragma unroll
    for (int cc = 0; cc < 4; ++cc) {
        if (cc < nc) {
            int sidx = (((u0 + cc) << 3) + b) * 64 + row;
            mv[cc] = stats[sidx * 2];
            lv[cc] = stats[sidx * 2 + 1];
            mstar = fmaxf(mstar, mv[cc]);
        }
    }
    float den = 0.f, wc[4];
#pragma unroll
    for (int cc = 0; cc < 4; ++cc) {
        if (cc < nc) { wc[cc] = __expf(mv[cc] - mstar) * lv[cc]; den += wc[cc]; }
        else wc[cc] = 0.f;
    }
    // a[(dt-2g)*16 + fr], dt in {2g, 2g+1}
    float a[32] = {};
#pragma unroll
    for (int cc = 0; cc < 4; ++cc) {
        if (cc < nc) {
            const _Float16* pp = part + ((((u0 + cc) << 3) + b) * 8192)
                                 + w * 2048 + r * 64 + fq * 16;
            float wcc = wc[cc];
#pragma unroll
            for (int dd = 0; dd < 2; ++dd) {
                half8 h0 = *(const half8*)(pp + (2 * g + dd) * 256);
                half8 h1 = *(const half8*)(pp + (2 * g + dd) * 256 + 8);
#pragma unroll
                for (int e = 0; e < 8; ++e) {
                    a[dd * 16 + e]     += wcc * (float)h0[e];
                    a[dd * 16 + 8 + e] += wcc * (float)h1[e];
                }
            }
        }
    }
    float id = 1.0f / den;
    float* op = out + (b * 2048 + qt * 64 + row) * 128 + g * 32;
#pragma unroll
    for (int uu = 0; uu < 8; ++uu) {
        float4 o;
        o.x = a[uu * 4]     * id;
        o.y = a[uu * 4 + 1] * id;
        o.z = a[uu * 4 + 2] * id;
        o.w = a[uu * 4 + 3] * id;
        *(float4*)(op + uu * 4) = o;
    }
}

extern "C" void kernel_launch(void* const* d_in, const int* in_sizes, int n_in,
                              void* d_out, int out_size, void* d_ws, size_t ws_size,
                              hipStream_t stream) {
    const float* x  = (const float*)d_in[0];
    const float* wq = (const float*)d_in[1];
    const float* wk = (const float*)d_in[2];
    const float* wv = (const float*)d_in[3];

    char* ws = (char*)d_ws;
    _Float16* wh   = (_Float16*)(ws);                    // 768 KB
    _Float16* qhp  = (_Float16*)(ws + (1u  << 20));      // 4 MB
    _Float16* khp  = (_Float16*)(ws + (5u  << 20));      // 4 MB
    _Float16* vtp  = (_Float16*)(ws + (9u  << 20));      // 4 MB
    _Float16* part = (_Float16*)(ws + (13u << 20));      // 640*16KB = 10.5 MB
    float*    stat = (float*)   (ws + (24u << 20));      // 328 KB

    wconv_k<<<192, 256, 0, stream>>>(wq, wk, wv, wh);
    qkv_k<<<512, 256, 0, stream>>>(x, wh, qhp, khp, vtp);
    attn_k<<<640, 256, 0, stream>>>(qhp, khp, vtp, part, stat, (float*)d_out);
    comb_k<<<192, 256, 0, stream>>>(part, stat, (float*)d_out);
}